// Round 7
// baseline (49.506 us; speedup 1.0000x reference)
//
#include <hip/hip_runtime.h>

namespace {

constexpr int T   = 16384;
constexpr int B   = 8;
constexpr int C4  = 64;              // 256 fp32 channels = 64 float4
constexpr int SUB = 8;               // outputs per wave
constexpr int WAVES = 4;             // block = 256 threads
constexpr int BLOCK_T = SUB * WAVES; // 32 outputs per block
constexpr int ROWS = BLOCK_T + 10;   // 42 staged rows (halo 5 each side)
constexpr int CHUNKS = T / BLOCK_T;  // 512 chunks per batch
constexpr int ROW_B = C4 * 16;       // 1024 bytes per row

typedef float vfloat4 __attribute__((ext_vector_type(4)));
typedef __attribute__((address_space(3))) void lds_void;
typedef const __attribute__((address_space(1))) void gbl_void;

__device__ __forceinline__ void stnt(float4* p, float4 v) {
    vfloat4 nv = {v.x, v.y, v.z, v.w};
    __builtin_nontemporal_store(nv, (vfloat4*)p);
}

__global__ __launch_bounds__(256) void runavg_kernel(const float4* __restrict__ x,
                                                     float4* __restrict__ out) {
    __shared__ float4 lds[ROWS * C4];   // 43008 B -> 3 blocks/CU

    const int tid  = threadIdx.x;
    const int lane = tid & 63;
    const int wid  = tid >> 6;
    const int b    = blockIdx.x / CHUNKS;
    const int t0b  = (blockIdx.x % CHUNKS) * BLOCK_T;

    const bool first = (t0b == 0);
    const bool last  = (t0b + BLOCK_T == T);
    const bool guard = first || last;

    // ---- stage 42 rows into LDS; iteration `it` stages row r = it*4+wid ----
    // row r holds time t = t0b - 5 + r. LDS dest is wave-uniform base
    // (+ lane*16 by HW); global source is per-lane (row base + lane*16).
    const float* xf = (const float*)x;
    #pragma unroll
    for (int it = 0; it < 11; ++it) {
        const int r = it * 4 + wid;
        if (r < ROWS) {
            const int t = t0b - 5 + r;
            if (!guard || ((unsigned)t < (unsigned)T)) {   // skip OOB rows (zeroed below)
                const float* gp = xf + ((size_t)b * T + t) * 256 + lane * 4;
                __builtin_amdgcn_global_load_lds((gbl_void*)gp,
                                                 (lds_void*)((char*)lds + r * ROW_B),
                                                 16, 0, 0);
            }
        }
    }

    // zero the skipped out-of-range rows (guard blocks only; block-uniform branch)
    if (guard) {
        const float4 z = make_float4(0.f, 0.f, 0.f, 0.f);
        for (int u = tid; u < 5 * C4; u += 256) {
            const int rr = u >> 6, cc = u & 63;
            if (first) lds[rr * C4 + cc] = z;                 // rows 0..4  (t = -5..-1)
            if (last)  lds[(ROWS - 5 + rr) * C4 + cc] = z;    // rows 37..41 (t = T..T+4)
        }
    }
    __syncthreads();   // drains global_load_lds (vmcnt) + the ds_writes

    // ---- compute: register-load this wave's 18-row window from LDS ----
    constexpr float INV = 1.0f / 11.0f;
    const int t0 = t0b + wid * SUB;
    float4 r[SUB + 10];
    #pragma unroll
    for (int i = 0; i < SUB + 10; ++i) {
        r[i] = lds[(wid * SUB + i) * C4 + lane];   // ds_read_b128, conflict-free stripe
    }
    __builtin_amdgcn_sched_barrier(0);

    float4* ob = out + ((size_t)b * T + t0) * C4 + lane;

    float4 s = {0.f, 0.f, 0.f, 0.f};
    #pragma unroll
    for (int i = 0; i < 11; ++i) {
        s.x += r[i].x; s.y += r[i].y; s.z += r[i].z; s.w += r[i].w;
    }
    float4 o;
    o.x = s.x * INV; o.y = s.y * INV; o.z = s.z * INV; o.w = s.w * INV;
    stnt(ob, o);

    #pragma unroll
    for (int i = 1; i < SUB; ++i) {
        const float4 a = r[i + 10];
        const float4 d = r[i - 1];
        s.x += a.x - d.x; s.y += a.y - d.y; s.z += a.z - d.z; s.w += a.w - d.w;
        o.x = s.x * INV; o.y = s.y * INV; o.z = s.z * INV; o.w = s.w * INV;
        stnt(ob + (size_t)i * C4, o);
    }
}

} // namespace

extern "C" void kernel_launch(void* const* d_in, const int* in_sizes, int n_in,
                              void* d_out, int out_size, void* d_ws, size_t ws_size,
                              hipStream_t stream) {
    const float4* x = (const float4*)d_in[0];
    float4* out = (float4*)d_out;
    const int grid = B * CHUNKS;   // 4096 blocks
    runavg_kernel<<<grid, 256, 0, stream>>>(x, out);
}

// Round 8
// 49.152 us; speedup vs baseline: 1.0072x; 1.0072x over previous
//
#include <hip/hip_runtime.h>

namespace {

constexpr int T   = 16384;
constexpr int B   = 8;
constexpr int C4  = 64;            // 256 fp32 channels as 64 float4
constexpr int SUB = 16;            // timesteps per wave
constexpr int NROWS = SUB + 10;    // 26 rows per chunk (halo 5 each side)
constexpr int WAVES_PER_BLOCK = 4; // block = 256 threads
constexpr int BLOCK_T = SUB * WAVES_PER_BLOCK; // 64 timesteps per block
constexpr int CHUNKS = T / BLOCK_T;            // 256 chunks per batch

typedef float vfloat4 __attribute__((ext_vector_type(4)));  // native clang vector

template <bool GUARD>
__device__ __forceinline__ float4 ldx(const float4* __restrict__ xb, int tt) {
    if (GUARD) {
        if (tt < 0 || tt >= T) return float4{0.f, 0.f, 0.f, 0.f};
    }
    return xb[(size_t)tt * C4];
}

__device__ __forceinline__ void stnt(float4* p, float4 v) {
    vfloat4 nv = {v.x, v.y, v.z, v.w};
    __builtin_nontemporal_store(nv, (vfloat4*)p);
}

template <bool GUARD>
__device__ __forceinline__ void run_chunk(const float4* __restrict__ xb,
                                          float4* __restrict__ ob, int t0) {
    constexpr float INV = 1.0f / 11.0f;

    // Prefetch all 26 rows. sched_barrier(0) forbids the scheduler from
    // sinking loads into the consumer chain (R2's failure mode: VGPR clamp
    // + re-serialization). 26 independent global_load_dwordx4 in flight.
    float4 r[NROWS];
    #pragma unroll
    for (int i = 0; i < NROWS; ++i) {
        r[i] = ldx<GUARD>(xb, t0 - 5 + i);
    }
    __builtin_amdgcn_sched_barrier(0);

    float4 s = {0.f, 0.f, 0.f, 0.f};
    #pragma unroll
    for (int i = 0; i < 11; ++i) {
        s.x += r[i].x; s.y += r[i].y; s.z += r[i].z; s.w += r[i].w;
    }
    float4 o;
    o.x = s.x * INV; o.y = s.y * INV; o.z = s.z * INV; o.w = s.w * INV;
    stnt(ob + (size_t)0, o);

    #pragma unroll
    for (int i = 1; i < SUB; ++i) {
        const float4 a = r[i + 10];
        const float4 d = r[i - 1];
        s.x += a.x - d.x; s.y += a.y - d.y; s.z += a.z - d.z; s.w += a.w - d.w;
        o.x = s.x * INV; o.y = s.y * INV; o.z = s.z * INV; o.w = s.w * INV;
        stnt(ob + (size_t)i * C4, o);
    }
}

__global__ __launch_bounds__(256, 2) void runavg_kernel(const float4* __restrict__ x,
                                                        float4* __restrict__ out) {
    const int lane = threadIdx.x & 63;   // channel-group (float4) index
    const int wid  = threadIdx.x >> 6;   // wave within block -> time sub-chunk
    const int b  = blockIdx.x / CHUNKS;
    const int t0 = (blockIdx.x % CHUNKS) * BLOCK_T + wid * SUB;

    const float4* __restrict__ xb = x   + (size_t)b * T * C4 + lane;
    float4* __restrict__       ob = out + ((size_t)b * T + t0) * C4 + lane;

    // fast path: every load in [t0-5, t0+SUB+4] is in-range
    if (t0 >= 5 && t0 + SUB + 5 <= T) {
        run_chunk<false>(xb, ob, t0);
    } else {
        run_chunk<true>(xb, ob, t0);
    }
}

} // namespace

extern "C" void kernel_launch(void* const* d_in, const int* in_sizes, int n_in,
                              void* d_out, int out_size, void* d_ws, size_t ws_size,
                              hipStream_t stream) {
    const float4* x = (const float4*)d_in[0];
    float4* out = (float4*)d_out;
    const int grid = B * CHUNKS;  // 2048 blocks
    runavg_kernel<<<grid, 256, 0, stream>>>(x, out);
}